// Round 1
// baseline (77563.995 us; speedup 1.0000x reference)
//
#include <hip/hip_runtime.h>
#include <hip/hip_bf16.h>
#include <math.h>

// ---------------------------------------------------------------------------
// Stacked LSTM: S=512, B=64, I=512, H=1024, L=4.
// Layer-by-layer: for each layer, 512 sequential step kernels, each doing
// z = [x_t; h_{t-1}] @ [Wx; Wh]^T-packed + b  via fp16 MFMA (fp32 accum),
// then fused activations + c/h update.
// Weights are pre-transposed to WT[col][k] fp16 so B-fragments are 16B
// contiguous loads. A (x / h rows) is row-major [64][K] fp16, A-fragments are
// 16B contiguous loads.
// ---------------------------------------------------------------------------

typedef _Float16 f16x8 __attribute__((ext_vector_type(8)));
typedef _Float16 f16x4 __attribute__((ext_vector_type(4)));
typedef float    f32x4 __attribute__((ext_vector_type(4)));

#define S_LEN 512
#define BATCH 64
#define HID   1024
#define GATES 4096

// ---------------- prep kernels ----------------

__global__ void conv_f32_f16(const float4* __restrict__ in,
                             f16x4* __restrict__ out, int n4) {
  int i = blockIdx.x * blockDim.x + threadIdx.x;
  if (i < n4) {
    float4 v = in[i];
    f16x4 o;
    o[0] = (_Float16)v.x; o[1] = (_Float16)v.y;
    o[2] = (_Float16)v.z; o[3] = (_Float16)v.w;
    out[i] = o;
  }
}

// dst[col][dstOff + k] = (f16) src[k][col], src is [srcK][4096] fp32 row-major.
__global__ void transpose_w(const float* __restrict__ src, int srcK,
                            _Float16* __restrict__ dst, int dstStride, int dstOff) {
  __shared__ float tile[64][65];
  const int kc0 = blockIdx.y * 64;   // src row (k) block
  const int c0  = blockIdx.x * 64;   // src col block
  const int tid = threadIdx.x;       // 256
  const int r4  = tid >> 6;          // 0..3
  const int cc  = tid & 63;          // 0..63
#pragma unroll
  for (int i = 0; i < 16; ++i) {
    int r = i * 4 + r4;
    tile[r][cc] = src[(size_t)(kc0 + r) * 4096 + c0 + cc];
  }
  __syncthreads();
#pragma unroll
  for (int i = 0; i < 16; ++i) {
    int c = i * 4 + r4;
    dst[(size_t)(c0 + c) * dstStride + dstOff + kc0 + cc] = (_Float16)tile[cc][c];
  }
}

// ---------------- LSTM step kernel ----------------
// grid = 64 WGs (one per 16 h-columns), block = 256 (4 waves, one 16-row tile
// each). Each WG computes z tiles for all 4 gates at its 16 columns, then the
// fused epilogue.

template <int KX>
__launch_bounds__(256)
__global__ void lstm_step(const _Float16* __restrict__ xin,    // [64][KX]
                          const _Float16* __restrict__ hprev,  // [64][1024] or null (t==0)
                          const _Float16* __restrict__ WT,     // [4096][KX+1024]
                          const float* __restrict__ bias,      // [4096]
                          float* __restrict__ cstate,          // [64][1024]
                          _Float16* __restrict__ hout16,       // [64][1024]
                          float* __restrict__ hout32,          // null unless last layer
                          float* __restrict__ hfin,            // null unless t==511
                          float* __restrict__ cfin) {
  constexpr int KTOT = KX + 1024;
  const int lane = threadIdx.x & 63;
  const int wave = threadIdx.x >> 6;
  const int n    = lane & 15;   // A row-in-tile, B/C col-in-tile
  const int quad = lane >> 4;
  const int j0   = blockIdx.x * 16;   // h-column base
  const int rowbase = wave * 16;      // batch-row base

  f32x4 acc[4] = {};

  // x-part: k in [0, KX)
  {
    const _Float16* ap = xin + (size_t)(rowbase + n) * KX + quad * 8;
#pragma unroll 4
    for (int k0 = 0; k0 < KX; k0 += 32) {
      f16x8 a = *(const f16x8*)(ap + k0);
#pragma unroll
      for (int g = 0; g < 4; ++g) {
        const _Float16* bp =
            WT + (size_t)(g * 1024 + j0 + n) * KTOT + k0 + quad * 8;
        f16x8 b = *(const f16x8*)bp;
        acc[g] = __builtin_amdgcn_mfma_f32_16x16x32_f16(a, b, acc[g], 0, 0, 0);
      }
    }
  }
  // h-part: k in [KX, KX+1024)
  if (hprev != nullptr) {
    const _Float16* ap = hprev + (size_t)(rowbase + n) * 1024 + quad * 8;
#pragma unroll 4
    for (int k0 = 0; k0 < 1024; k0 += 32) {
      f16x8 a = *(const f16x8*)(ap + k0);
#pragma unroll
      for (int g = 0; g < 4; ++g) {
        const _Float16* bp =
            WT + (size_t)(g * 1024 + j0 + n) * KTOT + KX + k0 + quad * 8;
        f16x8 b = *(const f16x8*)bp;
        acc[g] = __builtin_amdgcn_mfma_f32_16x16x32_f16(a, b, acc[g], 0, 0, 0);
      }
    }
  }

  // Epilogue: C/D layout col = lane&15, row = quad*4 + reg.
  const int col = j0 + n;
  const float bi = bias[col];
  const float bf = bias[1024 + col];
  const float bg = bias[2048 + col];
  const float bo = bias[3072 + col];
#pragma unroll
  for (int r = 0; r < 4; ++r) {
    const int row = rowbase + quad * 4 + r;
    const size_t idx = (size_t)row * 1024 + col;
    float zi = acc[0][r] + bi;
    float zf = acc[1][r] + bf;
    float zg = acc[2][r] + bg;
    float zo = acc[3][r] + bo;
    float ig = 1.0f / (1.0f + __expf(-zi));
    float fg = 1.0f / (1.0f + __expf(-zf));
    float gg = tanhf(zg);
    float og = 1.0f / (1.0f + __expf(-zo));
    float cn = fg * cstate[idx] + ig * gg;
    float h  = og * tanhf(cn);
    cstate[idx] = cn;
    hout16[idx] = (_Float16)h;
    if (hout32) hout32[idx] = h;
    if (hfin) { hfin[idx] = h; cfin[idx] = cn; }
  }
}

// ---------------- host ----------------

extern "C" void kernel_launch(void* const* d_in, const int* in_sizes, int n_in,
                              void* d_out, int out_size, void* d_ws, size_t ws_size,
                              hipStream_t stream) {
  const float* x_f32   = (const float*)d_in[0];  // [512,64,512]
  const float* Wx0     = (const float*)d_in[1];  // [512,4096]
  const float* Wh0     = (const float*)d_in[2];  // [1024,4096]
  const float* b0      = (const float*)d_in[3];  // [4096]
  const float* Wx_rest = (const float*)d_in[4];  // [3,1024,4096]
  const float* Wh_rest = (const float*)d_in[5];  // [3,1024,4096]
  const float* b_rest  = (const float*)d_in[6];  // [3,4096]

  float* out = (float*)d_out;
  float* hid_seq = out;                              // [512,64,1024]
  float* h_fin   = out + (size_t)S_LEN * BATCH * HID;        // [4,64,1024]
  float* c_fin   = h_fin + (size_t)4 * BATCH * HID;          // [4,64,1024]

  // workspace layout
  size_t off = 0;
  auto alloc = [&](size_t bytes) {
    void* p = (char*)d_ws + off;
    off += (bytes + 255) & ~(size_t)255;
    return p;
  };
  _Float16* WT[4];
  WT[0] = (_Float16*)alloc((size_t)GATES * 1536 * 2);
  WT[1] = (_Float16*)alloc((size_t)GATES * 2048 * 2);
  WT[2] = (_Float16*)alloc((size_t)GATES * 2048 * 2);
  WT[3] = (_Float16*)alloc((size_t)GATES * 2048 * 2);
  _Float16* x16  = (_Float16*)alloc((size_t)S_LEN * BATCH * 512 * 2);
  _Float16* seqA = (_Float16*)alloc((size_t)S_LEN * BATCH * HID * 2);
  _Float16* seqB = (_Float16*)alloc((size_t)S_LEN * BATCH * HID * 2);
  float* cst     = (float*)alloc((size_t)4 * BATCH * HID * 4);

  // zero c states
  hipMemsetAsync(cst, 0, (size_t)4 * BATCH * HID * 4, stream);

  // convert x to fp16
  {
    int n4 = S_LEN * BATCH * 512 / 4;
    conv_f32_f16<<<dim3((n4 + 255) / 256), dim3(256), 0, stream>>>(
        (const float4*)x_f32, (f16x4*)x16, n4);
  }

  // build fused transposed weights: WT_l[col][k], x rows first then h rows
  transpose_w<<<dim3(64, 512 / 64), dim3(256), 0, stream>>>(Wx0, 512, WT[0], 1536, 0);
  transpose_w<<<dim3(64, 1024 / 64), dim3(256), 0, stream>>>(Wh0, 1024, WT[0], 1536, 512);
  for (int l = 1; l < 4; ++l) {
    const float* wx = Wx_rest + (size_t)(l - 1) * 1024 * 4096;
    const float* wh = Wh_rest + (size_t)(l - 1) * 1024 * 4096;
    transpose_w<<<dim3(64, 1024 / 64), dim3(256), 0, stream>>>(wx, 1024, WT[l], 2048, 0);
    transpose_w<<<dim3(64, 1024 / 64), dim3(256), 0, stream>>>(wh, 1024, WT[l], 2048, 1024);
  }

  // sequential recurrence, layer by layer
  const size_t stepH = (size_t)BATCH * HID;  // 65536
  for (int l = 0; l < 4; ++l) {
    const _Float16* inseq;
    _Float16* outseq;
    int kx;
    if (l == 0)      { inseq = x16;  outseq = seqA; kx = 512; }
    else if (l == 1) { inseq = seqA; outseq = seqB; kx = 1024; }
    else if (l == 2) { inseq = seqB; outseq = seqA; kx = 1024; }
    else             { inseq = seqA; outseq = seqB; kx = 1024; }

    const float* bias = (l == 0) ? b0 : (b_rest + (size_t)(l - 1) * 4096);
    float* cs = cst + (size_t)l * stepH;

    for (int t = 0; t < S_LEN; ++t) {
      const _Float16* xin = inseq + (size_t)t * BATCH * (size_t)kx;
      const _Float16* hprev = (t == 0) ? nullptr : (outseq + (size_t)(t - 1) * stepH);
      _Float16* hout16 = outseq + (size_t)t * stepH;
      float* hout32 = (l == 3) ? (hid_seq + (size_t)t * stepH) : nullptr;
      float* hf = (t == S_LEN - 1) ? (h_fin + (size_t)l * stepH) : nullptr;
      float* cf = (t == S_LEN - 1) ? (c_fin + (size_t)l * stepH) : nullptr;
      if (l == 0) {
        lstm_step<512><<<dim3(64), dim3(256), 0, stream>>>(
            xin, hprev, WT[0], bias, cs, hout16, hout32, hf, cf);
      } else {
        lstm_step<1024><<<dim3(64), dim3(256), 0, stream>>>(
            xin, hprev, WT[l], bias, cs, hout16, hout32, hf, cf);
      }
    }
  }
}

// Round 2
// 71678.125 us; speedup vs baseline: 1.0821x; 1.0821x over previous
//
#include <hip/hip_runtime.h>
#include <hip/hip_cooperative_groups.h>
#include <hip/hip_bf16.h>
#include <math.h>

// ---------------------------------------------------------------------------
// Stacked LSTM S=512, B=64, I=512, H=1024, L=4 — persistent cooperative
// kernel per layer. 256 WGs; WG owns 8 h-cols (x4 gates = 32 gate-cols) and a
// 32-row batch half. Weights live in REGISTERS (each wave holds a K-quarter of
// the WG's 32 columns). Per timestep: K-split MFMA partials -> LDS reduce ->
// fused gate epilogue (c-state in registers across all 512 steps) ->
// grid.sync(). Eliminates 2048 kernel launches and all per-step weight
// traffic.
// ---------------------------------------------------------------------------

typedef _Float16 f16x8 __attribute__((ext_vector_type(8)));
typedef _Float16 f16x4 __attribute__((ext_vector_type(4)));
typedef float    f32x4 __attribute__((ext_vector_type(4)));

#define S_LEN 512
#define BATCH 64
#define HID   1024
#define GATES 4096

// ---------------- prep kernels ----------------

__global__ void conv_f32_f16(const float4* __restrict__ in,
                             f16x4* __restrict__ out, int n4) {
  int i = blockIdx.x * blockDim.x + threadIdx.x;
  if (i < n4) {
    float4 v = in[i];
    f16x4 o;
    o[0] = (_Float16)v.x; o[1] = (_Float16)v.y;
    o[2] = (_Float16)v.z; o[3] = (_Float16)v.w;
    out[i] = o;
  }
}

// dst[col][dstOff + k] = (f16) src[k][col], src is [srcK][4096] fp32 row-major.
__global__ void transpose_w(const float* __restrict__ src, int srcK,
                            _Float16* __restrict__ dst, int dstStride, int dstOff) {
  __shared__ float tile[64][65];
  const int kc0 = blockIdx.y * 64;
  const int c0  = blockIdx.x * 64;
  const int tid = threadIdx.x;
  const int r4  = tid >> 6;
  const int cc  = tid & 63;
#pragma unroll
  for (int i = 0; i < 16; ++i) {
    int r = i * 4 + r4;
    tile[r][cc] = src[(size_t)(kc0 + r) * 4096 + c0 + cc];
  }
  __syncthreads();
#pragma unroll
  for (int i = 0; i < 16; ++i) {
    int c = i * 4 + r4;
    dst[(size_t)(c0 + c) * dstStride + dstOff + kc0 + cc] = (_Float16)tile[cc][c];
  }
}

// ---------------- persistent per-layer LSTM kernel ----------------
// grid = 256 WGs x 256 threads. blockIdx.x: bit0 = batch half (32 rows),
// bits1.. = col group cg (8 h-cols). Wave w handles K-quarter
// [w*K/4,(w+1)*K/4) for all 32 rows x 32 packed gate-cols.
// Packed local col p = gate*8 + jloc  <->  WT col = gate*1024 + cg*8 + jloc.

template <int KX, bool LAST>
__launch_bounds__(256, 1)
__global__ void lstm_layer(const _Float16* __restrict__ inseq,  // [512][64][KX]
                           _Float16* __restrict__ outseq,       // [512][64][1024]
                           const _Float16* __restrict__ WT,     // [4096][KX+1024]
                           const float* __restrict__ bias,      // [4096]
                           float* __restrict__ hid32,           // [512][64][1024] if LAST
                           float* __restrict__ hfin,            // [64][1024]
                           float* __restrict__ cfin) {          // [64][1024]
  constexpr int KTOT = KX + 1024;
  constexpr int XI = KX / 128;   // x-part k0 iters per wave (KX/4/32)
  constexpr int HI = 8;          // h-part k0 iters per wave (1024/4/32)

  const int tid  = threadIdx.x;
  const int lane = tid & 63;
  const int w    = tid >> 6;     // wave = K-quarter
  const int n    = lane & 15;
  const int q    = lane >> 4;
  const int cg   = blockIdx.x >> 1;   // 0..127
  const int bg   = blockIdx.x & 1;    // batch half

  __shared__ float zred[4][32][33];

  // ---- load this wave's B fragments into registers (once per launch) ----
  f16x8 bx[XI][2], bh[HI][2];
#pragma unroll
  for (int ct = 0; ct < 2; ++ct) {
    const int p  = ct * 16 + n;
    const int sc = (p >> 3) * 1024 + cg * 8 + (p & 7);
    const _Float16* base = WT + (size_t)sc * KTOT;
#pragma unroll
    for (int i = 0; i < XI; ++i)
      bx[i][ct] = *(const f16x8*)(base + w * (KX / 4) + i * 32 + q * 8);
#pragma unroll
    for (int i = 0; i < HI; ++i)
      bh[i][ct] = *(const f16x8*)(base + KX + w * 256 + i * 32 + q * 8);
  }

  // ---- epilogue thread mapping: 256 threads = 32 rows x 8 h-cols ----
  const int erow  = tid >> 3;            // 0..31 local row
  const int ejl   = tid & 7;             // 0..7 local h-col
  const int grow  = bg * 32 + erow;      // global batch row
  const int ghcol = cg * 8 + ejl;        // global h col
  const float bi = bias[ghcol];
  const float bf = bias[1024 + ghcol];
  const float bgg = bias[2048 + ghcol];
  const float bo = bias[3072 + ghcol];
  float creg = 0.0f;

  cooperative_groups::grid_group grid = cooperative_groups::this_grid();

  const int arow0 = bg * 32 + n;         // A row for tile rt=0
  const int arow1 = bg * 32 + 16 + n;    // A row for tile rt=1

  for (int t = 0; t < S_LEN; ++t) {
    f32x4 acc00 = {}, acc01 = {}, acc10 = {}, acc11 = {};

    // x part
    {
      const _Float16* xt = inseq + (size_t)t * BATCH * KX;
      const _Float16* a0p = xt + (size_t)arow0 * KX + w * (KX / 4) + q * 8;
      const _Float16* a1p = xt + (size_t)arow1 * KX + w * (KX / 4) + q * 8;
#pragma unroll
      for (int i = 0; i < XI; ++i) {
        f16x8 a0 = *(const f16x8*)(a0p + i * 32);
        f16x8 a1 = *(const f16x8*)(a1p + i * 32);
        acc00 = __builtin_amdgcn_mfma_f32_16x16x32_f16(a0, bx[i][0], acc00, 0, 0, 0);
        acc01 = __builtin_amdgcn_mfma_f32_16x16x32_f16(a0, bx[i][1], acc01, 0, 0, 0);
        acc10 = __builtin_amdgcn_mfma_f32_16x16x32_f16(a1, bx[i][0], acc10, 0, 0, 0);
        acc11 = __builtin_amdgcn_mfma_f32_16x16x32_f16(a1, bx[i][1], acc11, 0, 0, 0);
      }
    }
    // h part (h_{-1} = 0)
    if (t > 0) {
      const _Float16* hp = outseq + (size_t)(t - 1) * BATCH * HID;
      const _Float16* a0p = hp + (size_t)arow0 * HID + w * 256 + q * 8;
      const _Float16* a1p = hp + (size_t)arow1 * HID + w * 256 + q * 8;
#pragma unroll
      for (int i = 0; i < HI; ++i) {
        f16x8 a0 = *(const f16x8*)(a0p + i * 32);
        f16x8 a1 = *(const f16x8*)(a1p + i * 32);
        acc00 = __builtin_amdgcn_mfma_f32_16x16x32_f16(a0, bh[i][0], acc00, 0, 0, 0);
        acc01 = __builtin_amdgcn_mfma_f32_16x16x32_f16(a0, bh[i][1], acc01, 0, 0, 0);
        acc10 = __builtin_amdgcn_mfma_f32_16x16x32_f16(a1, bh[i][0], acc10, 0, 0, 0);
        acc11 = __builtin_amdgcn_mfma_f32_16x16x32_f16(a1, bh[i][1], acc11, 0, 0, 0);
      }
    }

    // write K-partials: C/D layout row = q*4+r, col = ct*16+n
#pragma unroll
    for (int r = 0; r < 4; ++r) {
      zred[w][q * 4 + r][n]           = acc00[r];
      zred[w][q * 4 + r][16 + n]      = acc01[r];
      zred[w][16 + q * 4 + r][n]      = acc10[r];
      zred[w][16 + q * 4 + r][16 + n] = acc11[r];
    }
    __syncthreads();

    // fused reduction + gate epilogue (one output per thread)
    float zi = bi, zf = bf, zg = bgg, zo = bo;
#pragma unroll
    for (int ww = 0; ww < 4; ++ww) {
      zi += zred[ww][erow][ejl];
      zf += zred[ww][erow][8 + ejl];
      zg += zred[ww][erow][16 + ejl];
      zo += zred[ww][erow][24 + ejl];
    }
    float ig = 1.0f / (1.0f + __expf(-zi));
    float fg = 1.0f / (1.0f + __expf(-zf));
    float gg = tanhf(zg);
    float og = 1.0f / (1.0f + __expf(-zo));
    float cn = fg * creg + ig * gg;
    float h  = og * tanhf(cn);
    creg = cn;

    const size_t oidx = (size_t)grow * HID + ghcol;
    outseq[(size_t)t * BATCH * HID + oidx] = (_Float16)h;
    if (LAST) hid32[(size_t)t * BATCH * HID + oidx] = h;
    if (t == S_LEN - 1) { hfin[oidx] = h; cfin[oidx] = cn; }

    grid.sync();
  }
}

// ---------------- host ----------------

extern "C" void kernel_launch(void* const* d_in, const int* in_sizes, int n_in,
                              void* d_out, int out_size, void* d_ws, size_t ws_size,
                              hipStream_t stream) {
  const float* x_f32   = (const float*)d_in[0];
  const float* Wx0     = (const float*)d_in[1];
  const float* Wh0     = (const float*)d_in[2];
  const float* b0      = (const float*)d_in[3];
  const float* Wx_rest = (const float*)d_in[4];
  const float* Wh_rest = (const float*)d_in[5];
  const float* b_rest  = (const float*)d_in[6];

  float* out = (float*)d_out;
  float* hid_seq = out;                                     // [512,64,1024]
  float* h_fin   = out + (size_t)S_LEN * BATCH * HID;       // [4,64,1024]
  float* c_fin   = h_fin + (size_t)4 * BATCH * HID;         // [4,64,1024]

  size_t off = 0;
  auto alloc = [&](size_t bytes) {
    void* p = (char*)d_ws + off;
    off += (bytes + 255) & ~(size_t)255;
    return p;
  };
  _Float16* WT[4];
  WT[0] = (_Float16*)alloc((size_t)GATES * 1536 * 2);
  WT[1] = (_Float16*)alloc((size_t)GATES * 2048 * 2);
  WT[2] = (_Float16*)alloc((size_t)GATES * 2048 * 2);
  WT[3] = (_Float16*)alloc((size_t)GATES * 2048 * 2);
  _Float16* x16  = (_Float16*)alloc((size_t)S_LEN * BATCH * 512 * 2);
  _Float16* seqA = (_Float16*)alloc((size_t)S_LEN * BATCH * HID * 2);
  _Float16* seqB = (_Float16*)alloc((size_t)S_LEN * BATCH * HID * 2);

  // convert x to fp16
  {
    int n4 = S_LEN * BATCH * 512 / 4;
    conv_f32_f16<<<dim3((n4 + 255) / 256), dim3(256), 0, stream>>>(
        (const float4*)x_f32, (f16x4*)x16, n4);
  }

  // build fused transposed weights: WT_l[col][k], x rows first then h rows
  transpose_w<<<dim3(64, 512 / 64), dim3(256), 0, stream>>>(Wx0, 512, WT[0], 1536, 0);
  transpose_w<<<dim3(64, 1024 / 64), dim3(256), 0, stream>>>(Wh0, 1024, WT[0], 1536, 512);
  for (int l = 1; l < 4; ++l) {
    const float* wx = Wx_rest + (size_t)(l - 1) * 1024 * 4096;
    const float* wh = Wh_rest + (size_t)(l - 1) * 1024 * 4096;
    transpose_w<<<dim3(64, 1024 / 64), dim3(256), 0, stream>>>(wx, 1024, WT[l], 2048, 0);
    transpose_w<<<dim3(64, 1024 / 64), dim3(256), 0, stream>>>(wh, 1024, WT[l], 2048, 1024);
  }

  // 4 cooperative persistent launches, one per layer
  struct LayerCfg {
    const _Float16* in; _Float16* outp; const _Float16* wt; const float* b;
    float* hid; float* hf; float* cf; bool last; int kx;
  } cfg[4] = {
    { x16,  seqA, WT[0], b0,             nullptr, h_fin + 0 * 65536, c_fin + 0 * 65536, false, 512 },
    { seqA, seqB, WT[1], b_rest + 0*4096, nullptr, h_fin + 1 * 65536, c_fin + 1 * 65536, false, 1024 },
    { seqB, seqA, WT[2], b_rest + 1*4096, nullptr, h_fin + 2 * 65536, c_fin + 2 * 65536, false, 1024 },
    { seqA, seqB, WT[3], b_rest + 2*4096, hid_seq, h_fin + 3 * 65536, c_fin + 3 * 65536, true, 1024 },
  };

  for (int l = 0; l < 4; ++l) {
    const _Float16* pin = cfg[l].in;
    _Float16* pout = cfg[l].outp;
    const _Float16* pwt = cfg[l].wt;
    const float* pb = cfg[l].b;
    float* phid = cfg[l].hid;
    float* phf = cfg[l].hf;
    float* pcf = cfg[l].cf;
    void* args[7] = { &pin, &pout, &pwt, &pb, &phid, &phf, &pcf };
    if (cfg[l].kx == 512) {
      hipLaunchCooperativeKernel(reinterpret_cast<void*>(&lstm_layer<512, false>),
                                 dim3(256), dim3(256), args, 0, stream);
    } else if (!cfg[l].last) {
      hipLaunchCooperativeKernel(reinterpret_cast<void*>(&lstm_layer<1024, false>),
                                 dim3(256), dim3(256), args, 0, stream);
    } else {
      hipLaunchCooperativeKernel(reinterpret_cast<void*>(&lstm_layer<1024, true>),
                                 dim3(256), dim3(256), args, 0, stream);
    }
  }
}

// Round 3
// 24464.381 us; speedup vs baseline: 3.1705x; 2.9299x over previous
//
#include <hip/hip_runtime.h>
#include <hip/hip_bf16.h>
#include <math.h>

// ---------------------------------------------------------------------------
// Stacked LSTM S=512, B=64, I=512, H=1024, L=4 — persistent cooperative
// kernel per layer with a HAND-ROLLED device barrier (grid.sync() measured at
// ~37us/step; replaced by flag-array release/acquire barrier, ~2-3us).
// 256 WGs; WG owns 8 h-cols (x4 gates) x 32 batch rows; weights nominally in
// registers (compiler may reload from L2 - acceptable). Per step:
//   x-part MFMA (independent) -> barrier-wait(h_{t-1}) -> h-part MFMA ->
//   LDS K-reduce -> fused gate epilogue (c in regs) -> h store -> arrive.
// ---------------------------------------------------------------------------

typedef _Float16 f16x8 __attribute__((ext_vector_type(8)));
typedef _Float16 f16x4 __attribute__((ext_vector_type(4)));
typedef float    f32x4 __attribute__((ext_vector_type(4)));

#define S_LEN 512
#define BATCH 64
#define HID   1024
#define GATES 4096

// ---------------- prep kernels ----------------

__global__ void conv_f32_f16(const float4* __restrict__ in,
                             f16x4* __restrict__ out, int n4) {
  int i = blockIdx.x * blockDim.x + threadIdx.x;
  if (i < n4) {
    float4 v = in[i];
    f16x4 o;
    o[0] = (_Float16)v.x; o[1] = (_Float16)v.y;
    o[2] = (_Float16)v.z; o[3] = (_Float16)v.w;
    out[i] = o;
  }
}

// dst[col][dstOff + k] = (f16) src[k][col], src is [srcK][4096] fp32 row-major.
__global__ void transpose_w(const float* __restrict__ src, int srcK,
                            _Float16* __restrict__ dst, int dstStride, int dstOff) {
  __shared__ float tile[64][65];
  const int kc0 = blockIdx.y * 64;
  const int c0  = blockIdx.x * 64;
  const int tid = threadIdx.x;
  const int r4  = tid >> 6;
  const int cc  = tid & 63;
#pragma unroll
  for (int i = 0; i < 16; ++i) {
    int r = i * 4 + r4;
    tile[r][cc] = src[(size_t)(kc0 + r) * 4096 + c0 + cc];
  }
  __syncthreads();
#pragma unroll
  for (int i = 0; i < 16; ++i) {
    int c = i * 4 + r4;
    dst[(size_t)(c0 + c) * dstStride + dstOff + kc0 + cc] = (_Float16)tile[cc][c];
  }
}

// ---------------- fast device barrier ----------------
// flags: one int per WG (256). Monotone phase, no reset.
// arrive: syncthreads (drains all waves' stores to L2), then tid0 does a
// release store (buffer_wbl2 sc1 -> dirty lines reach IF$) to its flag.
// wait: thread i polls flags[i] with relaxed agent loads (read at coherence
// point, no per-poll invalidate), then one acquire fence (buffer_inv sc1).

__device__ __forceinline__ void bar_arrive(int* flags, int phase) {
  __syncthreads();
  if (threadIdx.x == 0)
    __hip_atomic_store(&flags[blockIdx.x], phase, __ATOMIC_RELEASE,
                       __HIP_MEMORY_SCOPE_AGENT);
}

__device__ __forceinline__ void bar_wait(int* flags, int phase) {
  while (__hip_atomic_load(&flags[threadIdx.x], __ATOMIC_RELAXED,
                           __HIP_MEMORY_SCOPE_AGENT) < phase) {}
  __syncthreads();
  if (threadIdx.x == 0) __builtin_amdgcn_fence(__ATOMIC_ACQUIRE, "agent");
  __syncthreads();
}

// ---------------- persistent per-layer LSTM kernel ----------------

template <int KX, bool LAST>
__launch_bounds__(256, 1)
__global__ void lstm_layer(const _Float16* __restrict__ inseq,  // [512][64][KX]
                           _Float16* __restrict__ outseq,       // [512][64][1024]
                           const _Float16* __restrict__ WT,     // [4096][KX+1024]
                           const float* __restrict__ bias,      // [4096]
                           float* __restrict__ hid32,           // if LAST
                           float* __restrict__ hfin,            // [64][1024]
                           float* __restrict__ cfin,            // [64][1024]
                           int* __restrict__ flags) {           // [256]
  constexpr int KTOT = KX + 1024;
  constexpr int XI = KX / 128;
  constexpr int HI = 8;

  const int tid  = threadIdx.x;
  const int lane = tid & 63;
  const int w    = tid >> 6;
  const int n    = lane & 15;
  const int q    = lane >> 4;
  const int cg   = blockIdx.x >> 1;
  const int bg   = blockIdx.x & 1;

  __shared__ float zred[4][32][33];

  // B fragments (wave w holds K-quarter of the WG's 32 packed gate-cols)
  f16x8 bx[XI][2], bh[HI][2];
#pragma unroll
  for (int ct = 0; ct < 2; ++ct) {
    const int p  = ct * 16 + n;
    const int sc = (p >> 3) * 1024 + cg * 8 + (p & 7);
    const _Float16* base = WT + (size_t)sc * KTOT;
#pragma unroll
    for (int i = 0; i < XI; ++i)
      bx[i][ct] = *(const f16x8*)(base + w * (KX / 4) + i * 32 + q * 8);
#pragma unroll
    for (int i = 0; i < HI; ++i)
      bh[i][ct] = *(const f16x8*)(base + KX + w * 256 + i * 32 + q * 8);
  }

  const int erow  = tid >> 3;
  const int ejl   = tid & 7;
  const int grow  = bg * 32 + erow;
  const int ghcol = cg * 8 + ejl;
  const float bi  = bias[ghcol];
  const float bf  = bias[1024 + ghcol];
  const float bgg = bias[2048 + ghcol];
  const float bo  = bias[3072 + ghcol];
  float creg = 0.0f;

  const int arow0 = bg * 32 + n;
  const int arow1 = bg * 32 + 16 + n;

  for (int t = 0; t < S_LEN; ++t) {
    f32x4 acc00 = {}, acc01 = {}, acc10 = {}, acc11 = {};

    // ---- x part (independent of the recurrence -> issued BEFORE the wait)
    {
      const _Float16* xt = inseq + (size_t)t * BATCH * KX;
      const _Float16* a0p = xt + (size_t)arow0 * KX + w * (KX / 4) + q * 8;
      const _Float16* a1p = xt + (size_t)arow1 * KX + w * (KX / 4) + q * 8;
#pragma unroll
      for (int i = 0; i < XI; ++i) {
        f16x8 a0 = *(const f16x8*)(a0p + i * 32);
        f16x8 a1 = *(const f16x8*)(a1p + i * 32);
        acc00 = __builtin_amdgcn_mfma_f32_16x16x32_f16(a0, bx[i][0], acc00, 0, 0, 0);
        acc01 = __builtin_amdgcn_mfma_f32_16x16x32_f16(a0, bx[i][1], acc01, 0, 0, 0);
        acc10 = __builtin_amdgcn_mfma_f32_16x16x32_f16(a1, bx[i][0], acc10, 0, 0, 0);
        acc11 = __builtin_amdgcn_mfma_f32_16x16x32_f16(a1, bx[i][1], acc11, 0, 0, 0);
      }
    }

    // ---- wait for h_{t-1} from all WGs
    if (t > 0) {
      bar_wait(flags, t);
      const _Float16* hp = outseq + (size_t)(t - 1) * BATCH * HID;
      const _Float16* a0p = hp + (size_t)arow0 * HID + w * 256 + q * 8;
      const _Float16* a1p = hp + (size_t)arow1 * HID + w * 256 + q * 8;
#pragma unroll
      for (int i = 0; i < HI; ++i) {
        f16x8 a0 = *(const f16x8*)(a0p + i * 32);
        f16x8 a1 = *(const f16x8*)(a1p + i * 32);
        acc00 = __builtin_amdgcn_mfma_f32_16x16x32_f16(a0, bh[i][0], acc00, 0, 0, 0);
        acc01 = __builtin_amdgcn_mfma_f32_16x16x32_f16(a0, bh[i][1], acc01, 0, 0, 0);
        acc10 = __builtin_amdgcn_mfma_f32_16x16x32_f16(a1, bh[i][0], acc10, 0, 0, 0);
        acc11 = __builtin_amdgcn_mfma_f32_16x16x32_f16(a1, bh[i][1], acc11, 0, 0, 0);
      }
    }

    // ---- K-partial reduce through LDS (C/D: row=q*4+r, col=ct*16+n)
#pragma unroll
    for (int r = 0; r < 4; ++r) {
      zred[w][q * 4 + r][n]           = acc00[r];
      zred[w][q * 4 + r][16 + n]      = acc01[r];
      zred[w][16 + q * 4 + r][n]      = acc10[r];
      zred[w][16 + q * 4 + r][16 + n] = acc11[r];
    }
    __syncthreads();

    float zi = bi, zf = bf, zg = bgg, zo = bo;
#pragma unroll
    for (int ww = 0; ww < 4; ++ww) {
      zi += zred[ww][erow][ejl];
      zf += zred[ww][erow][8 + ejl];
      zg += zred[ww][erow][16 + ejl];
      zo += zred[ww][erow][24 + ejl];
    }
    float ig = 1.0f / (1.0f + __expf(-zi));
    float fg = 1.0f / (1.0f + __expf(-zf));
    float gg = tanhf(zg);
    float og = 1.0f / (1.0f + __expf(-zo));
    float cn = fg * creg + ig * gg;
    float h  = og * tanhf(cn);
    creg = cn;

    const size_t oidx = (size_t)grow * HID + ghcol;
    outseq[(size_t)t * BATCH * HID + oidx] = (_Float16)h;
    if (LAST) hid32[(size_t)t * BATCH * HID + oidx] = h;
    if (t == S_LEN - 1) { hfin[oidx] = h; cfin[oidx] = cn; }

    if (t + 1 < S_LEN) bar_arrive(flags, t + 1);  // publish h_t
    else __syncthreads();
  }
}

// ---------------- host ----------------

extern "C" void kernel_launch(void* const* d_in, const int* in_sizes, int n_in,
                              void* d_out, int out_size, void* d_ws, size_t ws_size,
                              hipStream_t stream) {
  const float* x_f32   = (const float*)d_in[0];
  const float* Wx0     = (const float*)d_in[1];
  const float* Wh0     = (const float*)d_in[2];
  const float* b0      = (const float*)d_in[3];
  const float* Wx_rest = (const float*)d_in[4];
  const float* Wh_rest = (const float*)d_in[5];
  const float* b_rest  = (const float*)d_in[6];

  float* out = (float*)d_out;
  float* hid_seq = out;                                     // [512,64,1024]
  float* h_fin   = out + (size_t)S_LEN * BATCH * HID;       // [4,64,1024]
  float* c_fin   = h_fin + (size_t)4 * BATCH * HID;         // [4,64,1024]

  size_t off = 0;
  auto alloc = [&](size_t bytes) {
    void* p = (char*)d_ws + off;
    off += (bytes + 255) & ~(size_t)255;
    return p;
  };
  _Float16* WT[4];
  WT[0] = (_Float16*)alloc((size_t)GATES * 1536 * 2);
  WT[1] = (_Float16*)alloc((size_t)GATES * 2048 * 2);
  WT[2] = (_Float16*)alloc((size_t)GATES * 2048 * 2);
  WT[3] = (_Float16*)alloc((size_t)GATES * 2048 * 2);
  _Float16* x16  = (_Float16*)alloc((size_t)S_LEN * BATCH * 512 * 2);
  _Float16* seqA = (_Float16*)alloc((size_t)S_LEN * BATCH * HID * 2);
  _Float16* seqB = (_Float16*)alloc((size_t)S_LEN * BATCH * HID * 2);
  int* flags     = (int*)alloc(4 * 256 * sizeof(int));

  // zero barrier flags (ws is poisoned to 0xAA before every call)
  hipMemsetAsync(flags, 0, 4 * 256 * sizeof(int), stream);

  // convert x to fp16
  {
    int n4 = S_LEN * BATCH * 512 / 4;
    conv_f32_f16<<<dim3((n4 + 255) / 256), dim3(256), 0, stream>>>(
        (const float4*)x_f32, (f16x4*)x16, n4);
  }

  // fused transposed weights: WT_l[col][k], x rows then h rows
  transpose_w<<<dim3(64, 512 / 64), dim3(256), 0, stream>>>(Wx0, 512, WT[0], 1536, 0);
  transpose_w<<<dim3(64, 1024 / 64), dim3(256), 0, stream>>>(Wh0, 1024, WT[0], 1536, 512);
  for (int l = 1; l < 4; ++l) {
    const float* wx = Wx_rest + (size_t)(l - 1) * 1024 * 4096;
    const float* wh = Wh_rest + (size_t)(l - 1) * 1024 * 4096;
    transpose_w<<<dim3(64, 1024 / 64), dim3(256), 0, stream>>>(wx, 1024, WT[l], 2048, 0);
    transpose_w<<<dim3(64, 1024 / 64), dim3(256), 0, stream>>>(wh, 1024, WT[l], 2048, 1024);
  }

  struct LayerCfg {
    const _Float16* in; _Float16* outp; const _Float16* wt; const float* b;
    float* hid; float* hf; float* cf; int* flg; bool last; int kx;
  } cfg[4] = {
    { x16,  seqA, WT[0], b0,              nullptr, h_fin + 0 * 65536, c_fin + 0 * 65536, flags + 0 * 256, false, 512 },
    { seqA, seqB, WT[1], b_rest + 0*4096, nullptr, h_fin + 1 * 65536, c_fin + 1 * 65536, flags + 1 * 256, false, 1024 },
    { seqB, seqA, WT[2], b_rest + 1*4096, nullptr, h_fin + 2 * 65536, c_fin + 2 * 65536, flags + 2 * 256, false, 1024 },
    { seqA, seqB, WT[3], b_rest + 2*4096, hid_seq, h_fin + 3 * 65536, c_fin + 3 * 65536, flags + 3 * 256, true,  1024 },
  };

  for (int l = 0; l < 4; ++l) {
    const _Float16* pin = cfg[l].in;
    _Float16* pout = cfg[l].outp;
    const _Float16* pwt = cfg[l].wt;
    const float* pb = cfg[l].b;
    float* phid = cfg[l].hid;
    float* phf = cfg[l].hf;
    float* pcf = cfg[l].cf;
    int* pfl = cfg[l].flg;
    void* args[8] = { &pin, &pout, &pwt, &pb, &phid, &phf, &pcf, &pfl };
    if (cfg[l].kx == 512) {
      hipLaunchCooperativeKernel(reinterpret_cast<void*>(&lstm_layer<512, false>),
                                 dim3(256), dim3(256), args, 0, stream);
    } else if (!cfg[l].last) {
      hipLaunchCooperativeKernel(reinterpret_cast<void*>(&lstm_layer<1024, false>),
                                 dim3(256), dim3(256), args, 0, stream);
    } else {
      hipLaunchCooperativeKernel(reinterpret_cast<void*>(&lstm_layer<1024, true>),
                                 dim3(256), dim3(256), args, 0, stream);
    }
  }
}